// Round 1
// baseline (23165.176 us; speedup 1.0000x reference)
//
#include <hip/hip_runtime.h>
#include <hip/hip_bf16.h>

typedef __attribute__((ext_vector_type(8))) short short8;
typedef __attribute__((ext_vector_type(4))) float float4v;
typedef __attribute__((ext_vector_type(4))) unsigned int uint4v;
typedef unsigned short ushort_t;
typedef unsigned int uint_t;

#define BB 64      // batch
#define SS 512     // seq len
#define HH 1024    // hidden
#define AA 128     // actions
#define NWG 256    // recurrent workgroups (each owns 16 interleaved gate cols = 4 units)

// ws layout (bytes)
#define XSW_BYTES   67108864ULL                  // [s][kk0..31][rg0..3][lane0..63][j0..7] bf16
#define WSW_BYTES   16777216ULL                  // [g0..255][kk0..63][lane][j] bf16
#define HALL_BYTES  67239936ULL                  // [slot 0..512][kk0..31][rg][lane][j] bf16 (slot s+1 = h_s)
#define XSW_OFF     0ULL
#define WSW_OFF     (XSW_OFF + XSW_BYTES)
#define HALL_OFF    (WSW_OFF + WSW_BYTES)
#define FLAGS_OFF   (HALL_OFF + HALL_BYTES)

__device__ __forceinline__ ushort_t f2bf(float f) {
    union { float f; uint_t u; } v; v.f = f;
    uint_t u = v.u;
    return (ushort_t)((u + 0x7fffu + ((u >> 16) & 1u)) >> 16);
}

// ---------------- init: flags, Hall[0] (h_{-1}=0), output dummy blocks ----------------
__global__ void k_init(uint_t* __restrict__ flags, ushort_t* __restrict__ hall,
                       float* __restrict__ out) {
    int i = blockIdx.x * 256 + threadIdx.x;          // 32768 threads
    if (i < NWG) flags[i] = 0u;
    ((uint_t*)hall)[i] = 0u;                          // 65536 ushorts = 32768 uints
    out[i] = 0.0f;                                    // dummy block 0
    out[32768 + (size_t)BB * SS * AA + i] = 0.0f;     // dummy block 2
}

// ---------------- x_emb gather + bf16 + A-fragment swizzle ----------------
__global__ void k_prep_x(const float* __restrict__ embed, const int* __restrict__ x,
                         ushort_t* __restrict__ xsw) {
    int t = blockIdx.x * 256 + threadIdx.x;          // 4,194,304 threads = [s][kk][rg][lane]
    int lane = t & 63;
    int rg   = (t >> 6) & 3;
    int kk   = (t >> 8) & 31;
    int s    = t >> 13;
    int b  = rg * 16 + (lane & 15);
    int k0 = kk * 32 + (lane >> 4) * 8;
    int tok = x[b * SS + s];
    const float* src = embed + (size_t)tok * HH + k0;
    float4v v0 = *(const float4v*)src;
    float4v v1 = *(const float4v*)(src + 4);
    uint_t p0 = (uint_t)f2bf(v0[0]) | ((uint_t)f2bf(v0[1]) << 16);
    uint_t p1 = (uint_t)f2bf(v0[2]) | ((uint_t)f2bf(v0[3]) << 16);
    uint_t p2 = (uint_t)f2bf(v1[0]) | ((uint_t)f2bf(v1[1]) << 16);
    uint_t p3 = (uint_t)f2bf(v1[2]) | ((uint_t)f2bf(v1[3]) << 16);
    uint4v pk = {p0, p1, p2, p3};
    ((uint4v*)xsw)[t] = pk;
}

// ---------------- [Wi;Wh] -> bf16, gate-interleaved cols, B-fragment swizzle ----------------
__global__ void k_prep_w(const float* __restrict__ Wi, const float* __restrict__ Wh,
                         ushort_t* __restrict__ wsw) {
    int t = blockIdx.x * 256 + threadIdx.x;          // 8,388,608 threads = [k][q][u]
    int u = t & 1023;
    int q = (t >> 10) & 3;
    int k = t >> 12;                                 // 0..2047
    float v = (k < 1024) ? Wi[(size_t)k * 4096 + q * 1024 + u]
                         : Wh[(size_t)(k - 1024) * 4096 + q * 1024 + u];
    int g = u >> 2, du = u & 3;
    int c = du * 4 + q;                              // col-in-slice 0..15
    int kk = k >> 5, quad = (k >> 3) & 3, j = k & 7;
    int lane = quad * 16 + c;
    wsw[(((size_t)g * 64 + kk) * 64 + lane) * 8 + j] = f2bf(v);
}

// ---------------- persistent sequential LSTM scan ----------------
__global__ void __launch_bounds__(256)
k_lstm(const ushort_t* __restrict__ xsw, const ushort_t* __restrict__ wsw,
       ushort_t* hall, const float* __restrict__ bh, uint_t* flags) {
    __shared__ ushort_t wlds[64 * 64 * 8];           // 64 KiB: [kk0..63][lane][j]
    const int g    = blockIdx.x;
    const int tid  = threadIdx.x;
    const int lane = tid & 63;
    const int rg   = tid >> 6;                       // wave id = batch row-group

    {   // stage weight slice (coalesced 16B/lane)
        const uint4v* src = (const uint4v*)(wsw + (size_t)g * 64 * 64 * 8);
        uint4v* dst = (uint4v*)wlds;
        for (int i = tid; i < 4096; i += 256) dst[i] = src[i];
    }
    __syncthreads();

    const int c_idx = lane & 15;
    const int q  = c_idx & 3;
    const int du = c_idx >> 2;
    const int quad = lane >> 4;
    const int u = g * 4 + du;                        // hidden unit this lane group owns
    const float bhv = bh[q * 1024 + u];

    // h write coords (only q==0 lanes store)
    const int kk_h = u >> 5;
    const int quad_h = (u & 31) >> 3;
    const int j_h = u & 7;

    float cst0 = 0.f, cst1 = 0.f, cst2 = 0.f, cst3 = 0.f;  // c-state, 4 batch rows
    const short8* xbase = (const short8*)xsw;
    const short8* hbase = (const short8*)hall;
    const short8* wl = (const short8*)wlds + lane;

    for (int s = 0; s < SS; ++s) {
        float4v acc = {bhv, bhv, bhv, bhv};

        // ---- x-part (no dependency on h): overlaps the flag wait below ----
        const short8* xp = xbase + (((size_t)s * 32) * 4 + rg) * 64 + lane;
        #pragma unroll 8
        for (int kk = 0; kk < 32; ++kk) {
            short8 a  = xp[kk * 256];
            short8 b8 = wl[kk * 64];
            acc = __builtin_amdgcn_mfma_f32_16x16x32_bf16(a, b8, acc, 0, 0, 0);
        }

        // ---- wait until all WGs finished step s-1 (flags monotone) ----
        {
            bool ok;
            do {
                uint_t f = __hip_atomic_load(&flags[tid], __ATOMIC_RELAXED,
                                             __HIP_MEMORY_SCOPE_AGENT);
                ok = (f >= (uint_t)s);
            } while (!__syncthreads_and(ok));
            __threadfence();   // acquire: make Hall[s] writes visible / invalidate L1
        }

        // ---- h-part ----
        const short8* hp = hbase + (((size_t)s * 32) * 4 + rg) * 64 + lane;
        #pragma unroll 8
        for (int kk = 0; kk < 32; ++kk) {
            short8 a  = hp[kk * 256];
            short8 b8 = wl[(32 + kk) * 64];
            acc = __builtin_amdgcn_mfma_f32_16x16x32_bf16(a, b8, acc, 0, 0, 0);
        }

        // ---- elementwise LSTM update (gates for a unit live in 4 adjacent lanes) ----
        float hv[4];
        #pragma unroll
        for (int r = 0; r < 4; ++r) {
            float own = acc[r];
            float x1 = __shfl_xor(own, 1);
            float x2 = __shfl_xor(own, 2);
            float x3 = __shfl_xor(own, 3);
            float gi, gf, gg, go;
            if      (q == 0) { gi = own; gf = x1;  gg = x2;  go = x3;  }
            else if (q == 1) { gi = x1;  gf = own; gg = x3;  go = x2;  }
            else if (q == 2) { gi = x2;  gf = x3;  gg = own; go = x1;  }
            else             { gi = x3;  gf = x2;  gg = x1;  go = own; }
            gi = 1.f / (1.f + __expf(-gi));
            gf = 1.f / (1.f + __expf(-gf));
            go = 1.f / (1.f + __expf(-go));
            gg = tanhf(gg);
            float cv = (r == 0 ? cst0 : r == 1 ? cst1 : r == 2 ? cst2 : cst3);
            cv = gf * cv + gi * gg;
            if (r == 0) cst0 = cv; else if (r == 1) cst1 = cv;
            else if (r == 2) cst2 = cv; else cst3 = cv;
            hv[r] = go * tanhf(cv);
        }
        if (q == 0) {
            size_t base = ((((size_t)(s + 1) * 32 + kk_h) * 4 + rg) * 64) * 8 + j_h;
            #pragma unroll
            for (int r = 0; r < 4; ++r) {
                int lane_h = quad_h * 16 + quad * 4 + r;   // b&15 = quad*4+r
                hall[base + (size_t)lane_h * 8] = f2bf(hv[r]);
            }
        }
        __threadfence();   // release: h visible before flag
        __syncthreads();
        if (tid == 0)
            __hip_atomic_store(&flags[g], (uint_t)(s + 1), __ATOMIC_RELEASE,
                               __HIP_MEMORY_SCOPE_AGENT);
    }
}

// ---------------- head GEMM: logits[b][s][:] = h_s @ Wo + bo ----------------
__global__ void __launch_bounds__(256)
k_head(const ushort_t* __restrict__ hall, const float* __restrict__ Wo,
       const float* __restrict__ bo, float* __restrict__ out) {
    __shared__ ushort_t wlds[32 * 2 * 64 * 8];       // 64 KiB: [kk][nt][lane][j]
    const int wg = blockIdx.x;                       // 512 WGs: cg(4) x sg(128)
    const int cg = wg & 3, sg = wg >> 2;
    const int tid = threadIdx.x, lane = tid & 63, rg = tid >> 6;
    const int col0 = cg * 32;

    for (int i = tid; i < 32768; i += 256) {         // [k][col] -> B-frag swizzle
        int k = i >> 5;
        int col = i & 31;
        float v = Wo[(size_t)k * AA + col0 + col];
        int kk = k >> 5, quad = (k >> 3) & 3, j = k & 7;
        int nt = col >> 4, cl = col & 15;
        wlds[(((kk * 2 + nt) * 64) + quad * 16 + cl) * 8 + j] = f2bf(v);
    }
    __syncthreads();

    const int cl = lane & 15, quad = lane >> 4;
    const float bo0 = bo[col0 + cl];
    const float bo1 = bo[col0 + 16 + cl];
    const short8* wl = (const short8*)wlds + lane;

    for (int si = 0; si < 4; ++si) {
        int s = sg * 4 + si;
        float4v a0 = {bo0, bo0, bo0, bo0};
        float4v a1 = {bo1, bo1, bo1, bo1};
        const short8* hp = (const short8*)hall + (((size_t)(s + 1) * 32) * 4 + rg) * 64 + lane;
        #pragma unroll 8
        for (int kk = 0; kk < 32; ++kk) {
            short8 a = hp[kk * 256];
            a0 = __builtin_amdgcn_mfma_f32_16x16x32_bf16(a, wl[(kk * 2 + 0) * 64], a0, 0, 0, 0);
            a1 = __builtin_amdgcn_mfma_f32_16x16x32_bf16(a, wl[(kk * 2 + 1) * 64], a1, 0, 0, 0);
        }
        #pragma unroll
        for (int r = 0; r < 4; ++r) {
            int b = rg * 16 + quad * 4 + r;
            size_t o = 32768 + ((size_t)b * SS + s) * AA;
            out[o + col0 + cl]      = a0[r];
            out[o + col0 + 16 + cl] = a1[r];
        }
    }
}

extern "C" void kernel_launch(void* const* d_in, const int* in_sizes, int n_in,
                              void* d_out, int out_size, void* d_ws, size_t ws_size,
                              hipStream_t stream) {
    const float* embed = (const float*)d_in[0];
    const float* Wi    = (const float*)d_in[1];
    const float* Wh    = (const float*)d_in[2];
    const float* bh    = (const float*)d_in[3];
    const float* Wo    = (const float*)d_in[4];
    const float* bo    = (const float*)d_in[5];
    const int*   x     = (const int*)d_in[6];
    float* out = (float*)d_out;
    unsigned char* ws = (unsigned char*)d_ws;

    ushort_t* xsw  = (ushort_t*)(ws + XSW_OFF);
    ushort_t* wsw  = (ushort_t*)(ws + WSW_OFF);
    ushort_t* hall = (ushort_t*)(ws + HALL_OFF);
    uint_t*   flags = (uint_t*)(ws + FLAGS_OFF);

    k_init  <<<128,   256, 0, stream>>>(flags, hall, out);
    k_prep_x<<<16384, 256, 0, stream>>>(embed, x, xsw);
    k_prep_w<<<32768, 256, 0, stream>>>(Wi, Wh, wsw);
    k_lstm  <<<NWG,   256, 0, stream>>>(xsw, wsw, hall, bh, flags);
    k_head  <<<512,   256, 0, stream>>>(hall, Wo, bo, out);
}

// Round 2
// 2804.410 us; speedup vs baseline: 8.2603x; 8.2603x over previous
//
#include <hip/hip_runtime.h>
#include <hip/hip_bf16.h>

typedef __attribute__((ext_vector_type(8))) short short8;
typedef __attribute__((ext_vector_type(4))) float float4v;
typedef __attribute__((ext_vector_type(4))) unsigned int uint4v;
typedef unsigned short ushort_t;
typedef unsigned int uint_t;

#define BB 64      // batch
#define SS 512     // seq len
#define HH 1024    // hidden
#define AA 128     // actions
#define NWG 256    // recurrent workgroups (each owns 16 interleaved gate cols = 4 units)

// ws layout (bytes)
#define XSW_BYTES   67108864ULL                  // [s][kk0..31][rg0..3][lane0..63][j0..7] bf16
#define WSW_BYTES   16777216ULL                  // [g0..255][kk0..63][lane][j] bf16
#define HALL_BYTES  67239936ULL                  // [slot 0..512][kk0..31][rg][lane][j] bf16 (slot s+1 = h_s)
#define XSW_OFF     0ULL
#define WSW_OFF     (XSW_OFF + XSW_BYTES)
#define HALL_OFF    (WSW_OFF + WSW_BYTES)
#define FLAGS_OFF   (HALL_OFF + HALL_BYTES)

__device__ __forceinline__ ushort_t f2bf(float f) {
    union { float f; uint_t u; } v; v.f = f;
    uint_t u = v.u;
    return (ushort_t)((u + 0x7fffu + ((u >> 16) & 1u)) >> 16);
}

__device__ __forceinline__ float fast_sigmoid(float x) {
    // 1/(1+e^-x)
    return __builtin_amdgcn_rcpf(1.0f + __expf(-x));
}
__device__ __forceinline__ float fast_tanh(float x) {
    // 1 - 2/(1+e^{2x});  x->+inf: 1-0=1, x->-inf: 1-2=-1
    return 1.0f - 2.0f * __builtin_amdgcn_rcpf(1.0f + __expf(2.0f * x));
}

// ---------------- init: flags, Hall[0] (h_{-1}=0), output dummy blocks ----------------
__global__ void k_init(uint_t* __restrict__ flags, ushort_t* __restrict__ hall,
                       float* __restrict__ out) {
    int i = blockIdx.x * 256 + threadIdx.x;          // 32768 threads
    if (i < NWG) flags[i] = 0u;
    ((uint_t*)hall)[i] = 0u;                          // 65536 ushorts = 32768 uints
    out[i] = 0.0f;                                    // dummy block 0
    out[32768 + (size_t)BB * SS * AA + i] = 0.0f;     // dummy block 2
}

// ---------------- x_emb gather + bf16 + A-fragment swizzle ----------------
__global__ void k_prep_x(const float* __restrict__ embed, const int* __restrict__ x,
                         ushort_t* __restrict__ xsw) {
    int t = blockIdx.x * 256 + threadIdx.x;          // 4,194,304 threads = [s][kk][rg][lane]
    int lane = t & 63;
    int rg   = (t >> 6) & 3;
    int kk   = (t >> 8) & 31;
    int s    = t >> 13;
    int b  = rg * 16 + (lane & 15);
    int k0 = kk * 32 + (lane >> 4) * 8;
    int tok = x[b * SS + s];
    const float* src = embed + (size_t)tok * HH + k0;
    float4v v0 = *(const float4v*)src;
    float4v v1 = *(const float4v*)(src + 4);
    uint_t p0 = (uint_t)f2bf(v0[0]) | ((uint_t)f2bf(v0[1]) << 16);
    uint_t p1 = (uint_t)f2bf(v0[2]) | ((uint_t)f2bf(v0[3]) << 16);
    uint_t p2 = (uint_t)f2bf(v1[0]) | ((uint_t)f2bf(v1[1]) << 16);
    uint_t p3 = (uint_t)f2bf(v1[2]) | ((uint_t)f2bf(v1[3]) << 16);
    uint4v pk = {p0, p1, p2, p3};
    ((uint4v*)xsw)[t] = pk;
}

// ---------------- [Wi;Wh] -> bf16, gate-interleaved cols, B-fragment swizzle ----------------
__global__ void k_prep_w(const float* __restrict__ Wi, const float* __restrict__ Wh,
                         ushort_t* __restrict__ wsw) {
    int t = blockIdx.x * 256 + threadIdx.x;          // 8,388,608 threads = [k][q][u]
    int u = t & 1023;
    int q = (t >> 10) & 3;
    int k = t >> 12;                                 // 0..2047
    float v = (k < 1024) ? Wi[(size_t)k * 4096 + q * 1024 + u]
                         : Wh[(size_t)(k - 1024) * 4096 + q * 1024 + u];
    int g = u >> 2, du = u & 3;
    int c = du * 4 + q;                              // col-in-slice 0..15
    int kk = k >> 5, quad = (k >> 3) & 3, j = k & 7;
    int lane = quad * 16 + c;
    wsw[(((size_t)g * 64 + kk) * 64 + lane) * 8 + j] = f2bf(v);
}

// ---------------- persistent sequential LSTM scan ----------------
__global__ void __launch_bounds__(256)
k_lstm(const ushort_t* __restrict__ xsw, const ushort_t* __restrict__ wsw,
       ushort_t* hall, const float* __restrict__ bh, uint_t* flags) {
    __shared__ ushort_t wlds[64 * 64 * 8];           // 64 KiB: [kk0..63][lane][j]
    const int g    = blockIdx.x;
    const int tid  = threadIdx.x;
    const int lane = tid & 63;
    const int rg   = tid >> 6;                       // wave id = batch row-group

    {   // stage weight slice (coalesced 16B/lane)
        const uint4v* src = (const uint4v*)(wsw + (size_t)g * 64 * 64 * 8);
        uint4v* dst = (uint4v*)wlds;
        for (int i = tid; i < 4096; i += 256) dst[i] = src[i];
    }
    __syncthreads();

    const int c_idx = lane & 15;
    const int q  = c_idx & 3;
    const int du = c_idx >> 2;
    const int quad = lane >> 4;
    const int u = g * 4 + du;                        // hidden unit this lane group owns
    const float bhv = bh[q * 1024 + u];

    // h write coords (lanes with q==0 && du even store packed pairs)
    const int kk_h = u >> 5;
    const int quad_h = (u & 31) >> 3;
    const int j_h = u & 7;                            // even for storing lanes
    uint_t* hall32 = (uint_t*)hall;

    float cst0 = 0.f, cst1 = 0.f, cst2 = 0.f, cst3 = 0.f;  // c-state, 4 batch rows
    const short8* xbase = (const short8*)xsw;
    const short8* hbase = (const short8*)hall;
    const short8* wl = (const short8*)wlds + lane;

    for (int s = 0; s < SS; ++s) {
        float4v ac0 = {bhv, bhv, bhv, bhv};
        float4v ac1 = {0.f, 0.f, 0.f, 0.f};
        float4v ac2 = {0.f, 0.f, 0.f, 0.f};
        float4v ac3 = {0.f, 0.f, 0.f, 0.f};

        // ---- x-part (no dependency on h): overlaps the flag wait below ----
        const short8* xp = xbase + (((size_t)s * 32) * 4 + rg) * 64 + lane;
        #pragma unroll
        for (int kk = 0; kk < 32; kk += 4) {
            short8 a0 = xp[(kk + 0) * 256];
            short8 a1 = xp[(kk + 1) * 256];
            short8 a2 = xp[(kk + 2) * 256];
            short8 a3 = xp[(kk + 3) * 256];
            ac0 = __builtin_amdgcn_mfma_f32_16x16x32_bf16(a0, wl[(kk + 0) * 64], ac0, 0, 0, 0);
            ac1 = __builtin_amdgcn_mfma_f32_16x16x32_bf16(a1, wl[(kk + 1) * 64], ac1, 0, 0, 0);
            ac2 = __builtin_amdgcn_mfma_f32_16x16x32_bf16(a2, wl[(kk + 2) * 64], ac2, 0, 0, 0);
            ac3 = __builtin_amdgcn_mfma_f32_16x16x32_bf16(a3, wl[(kk + 3) * 64], ac3, 0, 0, 0);
        }

        // ---- wait until all WGs finished step s-1 (flags monotone, sc1 loads) ----
        {
            bool ok;
            do {
                uint_t f = __hip_atomic_load(&flags[tid], __ATOMIC_RELAXED,
                                             __HIP_MEMORY_SCOPE_AGENT);
                ok = (f >= (uint_t)s);
            } while (!__syncthreads_and(ok));
            asm volatile("" ::: "memory");   // no fence: h-writes traveled via sc1 (LLC)
        }

        // ---- h-part (normal cached loads; slot s is write-once, no stale copies) ----
        const short8* hp = hbase + (((size_t)s * 32) * 4 + rg) * 64 + lane;
        #pragma unroll
        for (int kk = 0; kk < 32; kk += 4) {
            short8 a0 = hp[(kk + 0) * 256];
            short8 a1 = hp[(kk + 1) * 256];
            short8 a2 = hp[(kk + 2) * 256];
            short8 a3 = hp[(kk + 3) * 256];
            ac0 = __builtin_amdgcn_mfma_f32_16x16x32_bf16(a0, wl[(32 + kk + 0) * 64], ac0, 0, 0, 0);
            ac1 = __builtin_amdgcn_mfma_f32_16x16x32_bf16(a1, wl[(32 + kk + 1) * 64], ac1, 0, 0, 0);
            ac2 = __builtin_amdgcn_mfma_f32_16x16x32_bf16(a2, wl[(32 + kk + 2) * 64], ac2, 0, 0, 0);
            ac3 = __builtin_amdgcn_mfma_f32_16x16x32_bf16(a3, wl[(32 + kk + 3) * 64], ac3, 0, 0, 0);
        }
        float4v acc = (ac0 + ac1) + (ac2 + ac3);

        // ---- elementwise LSTM update: activate own gate, then shuffle activated ----
        float hv[4];
        #pragma unroll
        for (int r = 0; r < 4; ++r) {
            float own = acc[r];
            float a = (q == 2) ? fast_tanh(own) : fast_sigmoid(own);
            float x1 = __shfl_xor(a, 1);
            float x2 = __shfl_xor(a, 2);
            float x3 = __shfl_xor(a, 3);
            float gi, gf, gg, go;
            if      (q == 0) { gi = a;  gf = x1; gg = x2; go = x3; }
            else if (q == 1) { gi = x1; gf = a;  gg = x3; go = x2; }
            else if (q == 2) { gi = x2; gf = x3; gg = a;  go = x1; }
            else             { gi = x3; gf = x2; gg = x1; go = a;  }
            float cv = (r == 0 ? cst0 : r == 1 ? cst1 : r == 2 ? cst2 : cst3);
            cv = gf * cv + gi * gg;
            if (r == 0) cst0 = cv; else if (r == 1) cst1 = cv;
            else if (r == 2) cst2 = cv; else cst3 = cv;
            hv[r] = go * fast_tanh(cv);
        }

        // ---- pack (even u, odd u) bf16 pair -> one dword sc1 store to LLC ----
        float pv0 = __shfl_xor(hv[0], 4);
        float pv1 = __shfl_xor(hv[1], 4);
        float pv2 = __shfl_xor(hv[2], 4);
        float pv3 = __shfl_xor(hv[3], 4);
        if (q == 0 && (du & 1) == 0) {
            float pv[4] = {pv0, pv1, pv2, pv3};
            size_t base = (((size_t)(s + 1) * 32 + kk_h) * 4 + rg) * 64;
            #pragma unroll
            for (int r = 0; r < 4; ++r) {
                uint_t packed = (uint_t)f2bf(hv[r]) | ((uint_t)f2bf(pv[r]) << 16);
                int lane_h = quad_h * 16 + quad * 4 + r;
                size_t idx = ((base + (size_t)lane_h) * 8 + j_h) >> 1;
                __hip_atomic_store(&hall32[idx], packed, __ATOMIC_RELAXED,
                                   __HIP_MEMORY_SCOPE_AGENT);
            }
        }
        // __syncthreads drains vmcnt(0) for ALL waves (HW release), then post flag
        __syncthreads();
        if (tid == 0)
            __hip_atomic_store(&flags[g], (uint_t)(s + 1), __ATOMIC_RELAXED,
                               __HIP_MEMORY_SCOPE_AGENT);
    }
}

// ---------------- head GEMM: logits[b][s][:] = h_s @ Wo + bo ----------------
__global__ void __launch_bounds__(256)
k_head(const ushort_t* __restrict__ hall, const float* __restrict__ Wo,
       const float* __restrict__ bo, float* __restrict__ out) {
    __shared__ ushort_t wlds[32 * 2 * 64 * 8];       // 64 KiB: [kk][nt][lane][j]
    const int wg = blockIdx.x;                       // 512 WGs: cg(4) x sg(128)
    const int cg = wg & 3, sg = wg >> 2;
    const int tid = threadIdx.x, lane = tid & 63, rg = tid >> 6;
    const int col0 = cg * 32;

    for (int i = tid; i < 32768; i += 256) {         // [k][col] -> B-frag swizzle
        int k = i >> 5;
        int col = i & 31;
        float v = Wo[(size_t)k * AA + col0 + col];
        int kk = k >> 5, quad = (k >> 3) & 3, j = k & 7;
        int nt = col >> 4, cl = col & 15;
        wlds[(((kk * 2 + nt) * 64) + quad * 16 + cl) * 8 + j] = f2bf(v);
    }
    __syncthreads();

    const int cl = lane & 15, quad = lane >> 4;
    const float bo0 = bo[col0 + cl];
    const float bo1 = bo[col0 + 16 + cl];
    const short8* wl = (const short8*)wlds + lane;

    for (int si = 0; si < 4; ++si) {
        int s = sg * 4 + si;
        float4v a0 = {bo0, bo0, bo0, bo0};
        float4v a1 = {bo1, bo1, bo1, bo1};
        const short8* hp = (const short8*)hall + (((size_t)(s + 1) * 32) * 4 + rg) * 64 + lane;
        #pragma unroll 8
        for (int kk = 0; kk < 32; ++kk) {
            short8 a = hp[kk * 256];
            a0 = __builtin_amdgcn_mfma_f32_16x16x32_bf16(a, wl[(kk * 2 + 0) * 64], a0, 0, 0, 0);
            a1 = __builtin_amdgcn_mfma_f32_16x16x32_bf16(a, wl[(kk * 2 + 1) * 64], a1, 0, 0, 0);
        }
        #pragma unroll
        for (int r = 0; r < 4; ++r) {
            int b = rg * 16 + quad * 4 + r;
            size_t o = 32768 + ((size_t)b * SS + s) * AA;
            out[o + col0 + cl]      = a0[r];
            out[o + col0 + 16 + cl] = a1[r];
        }
    }
}

extern "C" void kernel_launch(void* const* d_in, const int* in_sizes, int n_in,
                              void* d_out, int out_size, void* d_ws, size_t ws_size,
                              hipStream_t stream) {
    const float* embed = (const float*)d_in[0];
    const float* Wi    = (const float*)d_in[1];
    const float* Wh    = (const float*)d_in[2];
    const float* bh    = (const float*)d_in[3];
    const float* Wo    = (const float*)d_in[4];
    const float* bo    = (const float*)d_in[5];
    const int*   x     = (const int*)d_in[6];
    float* out = (float*)d_out;
    unsigned char* ws = (unsigned char*)d_ws;

    ushort_t* xsw  = (ushort_t*)(ws + XSW_OFF);
    ushort_t* wsw  = (ushort_t*)(ws + WSW_OFF);
    ushort_t* hall = (ushort_t*)(ws + HALL_OFF);
    uint_t*   flags = (uint_t*)(ws + FLAGS_OFF);

    k_init  <<<128,   256, 0, stream>>>(flags, hall, out);
    k_prep_x<<<16384, 256, 0, stream>>>(embed, x, xsw);
    k_prep_w<<<32768, 256, 0, stream>>>(Wi, Wh, wsw);
    k_lstm  <<<NWG,   256, 0, stream>>>(xsw, wsw, hall, bh, flags);
    k_head  <<<512,   256, 0, stream>>>(hall, Wo, bo, out);
}